// Round 6
// baseline (611.431 us; speedup 1.0000x reference)
//
#include <hip/hip_runtime.h>
#include <stdint.h>

#define BB 2
#define DD 64
#define HH 128
#define WW 128
#define NVOX (DD*HH*WW)        // 2^20 per batch
#define TOTAL (BB*NVOX)        // 2097152
#define INF16 65535
#define HBINS 36868            // > max finite dsq (36227)
#define LBINS 512
#define NSMALL 7
#define CHUNK 256
#define NCH ((HBINS + CHUNK - 1) / CHUNK)      // 145
#define HISTINTS (4*HBINS + 4*NSMALL*LBINS)    // bigh||smallh contiguous
#define NB 256
#define NT 1024
#define TPITCH 132   // ushort pitch for xy tile
#define ZPITCH 68    // ushort pitch for z tile

// ---------------- device-scope grid barrier (phase-counting) ---------------
// All NB=256 blocks are co-resident (1 block/CU on 256 CUs), so spinning is
// deadlock-free. Counter is zeroed by hipMemsetAsync before each launch.
__device__ __forceinline__ void gridbar(int* cnt, int phase)
{
    __threadfence();                     // release: make our writes visible device-wide
    __syncthreads();
    if (threadIdx.x == 0) {
        __hip_atomic_fetch_add(cnt, 1, __ATOMIC_ACQ_REL, __HIP_MEMORY_SCOPE_AGENT);
        int target = phase * NB;
        while (__hip_atomic_load(cnt, __ATOMIC_ACQUIRE, __HIP_MEMORY_SCOPE_AGENT) < target) {
            __builtin_amdgcn_s_sleep(8);
        }
    }
    __syncthreads();
    __threadfence();                     // acquire: invalidate caches, see others' writes
}

// ---------- nearest set bit at position >= x in 128-bit mask (hi:lo) -------
__device__ __forceinline__ int dist128(uint64_t lo, uint64_t hi, int x)
{
    uint64_t a, b;
    if (x == 0)      { a = lo; b = hi; }
    else if (x < 64) { a = (lo >> x) | (hi << (64 - x)); b = hi >> x; }
    else             { a = hi >> (x - 64); b = 0; }
    if (a) return __builtin_ctzll(a);
    if (b) return 64 + __builtin_ctzll(b);
    return 999;
}

union SMem {
    uint16_t t16[HH * TPITCH];                               // phase 1 (33792 B)
    struct { uint16_t tile[DD * ZPITCH]; int lh[LBINS]; } zh; // phase 2
    int red[NT];                                             // phase 3
    struct { int ps[256]; int chunkidx, chunkbase, sel[2]; } pc; // phase 4
};

__global__ __launch_bounds__(NT, 4)
void hd95_mono(const float* __restrict__ pred, const float* __restrict__ targ,
               uint8_t* __restrict__ ep, uint8_t* __restrict__ eg,
               uint16_t* __restrict__ d0, uint16_t* __restrict__ d1,
               int* __restrict__ bigh, int* __restrict__ smallh,
               int* __restrict__ psum, float* __restrict__ out,
               int* __restrict__ bar)
{
    __shared__ SMem sm;
    int gid = blockIdx.x, tid = threadIdx.x;
    int gt = gid * NT + tid;

    // ---------------- phase 0: zero hist + edges --------------------------
    for (int t = gt; t < HISTINTS; t += NB * NT) bigh[t] = 0;

    for (int i = gt; i < TOTAL / 4; i += NB * NT) {
        int idx = i * 4;
        int x0 = idx & (WW-1);
        int y  = (idx >> 7) & (HH-1);
        int z  = (idx >> 14) & (DD-1);
        const float* srcs[2] = {pred, targ};
        uint32_t* dsts[2] = {(uint32_t*)ep, (uint32_t*)eg};
        const float4 zero4 = make_float4(0.f, 0.f, 0.f, 0.f);
        #pragma unroll
        for (int s = 0; s < 2; ++s) {
            const float* src = srcs[s];
            const float4* src4 = (const float4*)src;
            float4 c = src4[i];
            float lft = (x0 > 0)      ? src[idx - 1] : 0.f;
            float rgt = (x0 + 4 < WW) ? src[idx + 4] : 0.f;
            float4 ym = (y > 0)    ? src4[i - WW/4]      : zero4;
            float4 yp = (y < HH-1) ? src4[i + WW/4]      : zero4;
            float4 zm = (z > 0)    ? src4[i - (HH*WW)/4] : zero4;
            float4 zp = (z < DD-1) ? src4[i + (HH*WW)/4] : zero4;
            bool m0 = c.x > 0.5f, m1 = c.y > 0.5f, m2 = c.z > 0.5f, m3 = c.w > 0.5f;
            bool e0 = m0 && !((lft>0.5f) && m1 && (ym.x>0.5f) && (yp.x>0.5f) && (zm.x>0.5f) && (zp.x>0.5f));
            bool e1 = m1 && !(m0 && m2 && (ym.y>0.5f) && (yp.y>0.5f) && (zm.y>0.5f) && (zp.y>0.5f));
            bool e2 = m2 && !(m1 && m3 && (ym.z>0.5f) && (yp.z>0.5f) && (zm.z>0.5f) && (zp.z>0.5f));
            bool e3 = m3 && !(m2 && (rgt>0.5f) && (ym.w>0.5f) && (yp.w>0.5f) && (zm.w>0.5f) && (zp.w>0.5f));
            dsts[s][i] = (uint32_t)e0 | ((uint32_t)e1 << 8) | ((uint32_t)e2 << 16) | ((uint32_t)e3 << 24);
        }
    }

    gridbar(bar, 1);

    // ---------------- phase 1: fused x+y EDT (one slice-dir per block) ----
    {
        int dir = gid & 1;
        int bz  = gid >> 1;              // b*DD + z
        const uint8_t* mask = dir ? ep : eg;   // dir0: EDT of gt edges
        uint16_t* dout = dir ? d1 : d0;
        size_t sbase = (size_t)bz * (HH * WW);
        int row = tid >> 3;              // 0..127 (y)
        int seg = tid & 7;               // 16 bytes each

        uint4 mv = ((const uint4*)(mask + sbase))[tid];
        uint32_t b0 = ((mv.x & 0x01010101u) * 0x01020408u) >> 24;
        uint32_t b1 = ((mv.y & 0x01010101u) * 0x01020408u) >> 24;
        uint32_t b2 = ((mv.z & 0x01010101u) * 0x01020408u) >> 24;
        uint32_t b3 = ((mv.w & 0x01010101u) * 0x01020408u) >> 24;
        int bits16 = (int)(b0 | (b1 << 4) | (b2 << 8) | (b3 << 12));
        int lanebase = (tid & 63) & ~7;
        uint64_t lo = 0, hi = 0;
        #pragma unroll
        for (int j = 0; j < 4; ++j) {
            lo |= ((uint64_t)((uint32_t)__shfl(bits16, lanebase + j, 64) & 0xFFFFu)) << (16 * j);
            hi |= ((uint64_t)((uint32_t)__shfl(bits16, lanebase + 4 + j, 64) & 0xFFFFu)) << (16 * j);
        }
        uint64_t rlo = __brevll(hi), rhi = __brevll(lo);

        #pragma unroll
        for (int j = 0; j < 16; ++j) {
            int x = seg * 16 + j;
            int dr = dist128(lo, hi, x);
            int dl = dist128(rlo, rhi, 127 - x);
            int dist = min(dr, dl);
            int dsq = (dist > 127) ? INF16 : dist * dist;
            sm.t16[row * TPITCH + x] = (uint16_t)dsq;
        }
        __syncthreads();

        int xx = tid & 127;
        int yg = tid >> 7;               // 0..7
        for (int k = 0; k < 16; ++k) {
            int y = yg + k * 8;
            int best = sm.t16[y * TPITCH + xx];
            for (int o = 1; o < HH && o * o < best; ++o) {
                int osq = o * o;
                int ylo = y - o, yhi = y + o;
                if (ylo >= 0) best = min(best, (int)sm.t16[ylo * TPITCH + xx] + osq);
                if (yhi < HH) best = min(best, (int)sm.t16[yhi * TPITCH + xx] + osq);
            }
            dout[sbase + (size_t)y * WW + xx] = (uint16_t)best;
        }
    }

    gridbar(bar, 2);

    // ---------------- phase 2: z EDT + histogram (4 units per block) ------
    for (int k_u = 0; k_u < 4; ++k_u) {
        int u = gid + NB * k_u;          // dir | xt<<1 | y<<2 | b<<9
        __syncthreads();
        if (tid < LBINS) sm.zh.lh[tid] = 0;

        int dir = u & 1;
        int xt  = (u >> 1) & 1;
        int y   = (u >> 2) & 127;
        int b   = u >> 9;
        const uint16_t* d = dir ? d1 : d0;
        const uint8_t* evalmask = dir ? eg : ep;  // dir0: histogram at pred edges
        size_t base = (size_t)b * NVOX + (size_t)y * WW + xt * 64;

        {   // cooperative tile load: 64 z-rows x 128B
            int z = tid >> 4, sg = tid & 15;
            uint2 v = *(const uint2*)(d + base + (size_t)z * (HH * WW) + sg * 4);
            *(uint2*)&sm.zh.tile[z * ZPITCH + sg * 4] = v;
        }
        __syncthreads();

        int xx = tid & 63;
        int zg = tid >> 6;               // 0..15
        int g = b * 2 + dir;
        int* gbig = bigh + (size_t)g * HBINS;
        int lane = tid & 63;

        #pragma unroll
        for (int k = 0; k < 4; ++k) {
            int z = zg + k * 16;
            int best = sm.zh.tile[z * ZPITCH + xx];
            for (int o = 1; o < DD && o * o < best; ++o) {
                int osq = o * o;
                int zlo = z - o, zhi = z + o;
                if (zlo >= 0) best = min(best, (int)sm.zh.tile[zlo * ZPITCH + xx] + osq);
                if (zhi < DD) best = min(best, (int)sm.zh.tile[zhi * ZPITCH + xx] + osq);
            }
            int v = best; if (v >= HBINS) v = HBINS - 1;
            bool valid = evalmask[base + (size_t)z * (HH * WW) + xx] != 0;
            unsigned long long active = __ballot(valid);
            while (active) {
                int leader = __ffsll(active) - 1;
                int lv = __shfl(v, leader, 64);
                unsigned long long same = __ballot(valid && (v == lv));
                if (lane == leader) {
                    int cnt = __popcll(same);
                    if (lv < LBINS) atomicAdd(&sm.zh.lh[lv], cnt);
                    else            atomicAdd(&gbig[lv], cnt);
                }
                active &= ~same;
            }
        }
        __syncthreads();
        int slot = (u >> 1) & 7;
        int* dst = (slot == 0) ? gbig : (smallh + ((size_t)g * NSMALL + (slot - 1)) * LBINS);
        if (tid < LBINS) {
            int c = sm.zh.lh[tid];
            if (c) atomicAdd(&dst[tid], c);
        }
    }

    gridbar(bar, 3);

    // ---------------- phase 3: fold shadows + per-chunk sums --------------
    if (gid < 4 * 37) {
        int g = gid / 37, sc = gid % 37;
        int t = sc * 1024 + tid;
        int v = 0;
        if (t < HBINS) {
            size_t bi = (size_t)g * HBINS + t;
            v = bigh[bi];
            if (t < LBINS) {
                const int* gs = smallh + (size_t)g * NSMALL * LBINS + t;
                #pragma unroll
                for (int s = 0; s < NSMALL; ++s) v += gs[s * LBINS];
                bigh[bi] = v;
            }
        }
        sm.red[tid] = v;
        __syncthreads();
        for (int o = 128; o > 0; o >>= 1) {
            if ((tid & 255) < o) sm.red[tid] += sm.red[tid + o];
            __syncthreads();
        }
        int chunkid = sc * 4 + (tid >> 8);
        if ((tid & 255) == 0 && chunkid < NCH) psum[g * NCH + chunkid] = sm.red[tid];
    }

    gridbar(bar, 4);

    // ---------------- phase 4: percentile + final max ---------------------
    if (gid < 4) {
        int g = gid;
        int myv = (tid < NCH) ? psum[g * NCH + tid] : 0;
        if (tid < 256) sm.pc.ps[tid] = myv;
        if (tid == 0) { sm.pc.chunkidx = 0; sm.pc.chunkbase = 0; sm.pc.sel[0] = 0; sm.pc.sel[1] = 0; }
        __syncthreads();
        for (int o = 1; o < 256; o <<= 1) {
            int t = (tid >= o && tid < 256) ? sm.pc.ps[tid - o] : 0;
            __syncthreads();
            if (tid < 256) sm.pc.ps[tid] += t;
            __syncthreads();
        }
        int n = sm.pc.ps[255];
        int incl = (tid < 256) ? sm.pc.ps[tid] : 0;
        int excl = incl - myv;

        float pos = 0.95f * (float)(n - 1);
        float fpos = floorf(pos);
        int lo = (int)fpos;
        int nm1 = n - 1; if (nm1 < 0) nm1 = 0;
        if (lo < 0) lo = 0;
        if (lo > nm1) lo = nm1;
        int hi = lo + 1; if (hi > nm1) hi = nm1;
        float frac = pos - fpos;

        for (int ri = 0; ri < 2; ++ri) {
            int r = ri ? hi : lo;
            if (tid < 256 && r >= excl && r < incl) {   // unique owner
                sm.pc.chunkidx = tid; sm.pc.chunkbase = excl;
            }
            __syncthreads();
            int c = sm.pc.chunkidx, base = sm.pc.chunkbase;
            int t2 = c * CHUNK + tid;
            int cnt = (tid < 256 && t2 < HBINS) ? bigh[(size_t)g * HBINS + t2] : 0;
            __syncthreads();
            if (tid < 256) sm.pc.ps[tid] = cnt;
            __syncthreads();
            for (int o = 1; o < 256; o <<= 1) {
                int t = (tid >= o && tid < 256) ? sm.pc.ps[tid - o] : 0;
                __syncthreads();
                if (tid < 256) sm.pc.ps[tid] += t;
                __syncthreads();
            }
            if (tid < 256) {
                int incl2 = base + sm.pc.ps[tid];
                int excl2 = incl2 - cnt;
                if (r >= excl2 && r < incl2) sm.pc.sel[ri] = t2;
            }
            __syncthreads();
        }
        if (tid == 0) {
            float a = sqrtf((float)sm.pc.sel[0]);
            float bv = sqrtf((float)sm.pc.sel[1]);
            float val = a + frac * (bv - a);
            atomicMax((int*)out + (g >> 1), __float_as_int(val));  // val>=0: int order ok
        }
    }
}

extern "C" void kernel_launch(void* const* d_in, const int* in_sizes, int n_in,
                              void* d_out, int out_size, void* d_ws, size_t ws_size,
                              hipStream_t stream)
{
    const float* pred = (const float*)d_in[0];
    const float* targ = (const float*)d_in[1];
    float* out = (float*)d_out;

    uint8_t* ws = (uint8_t*)d_ws;
    uint8_t* ep  = ws;                               // TOTAL bytes
    uint8_t* eg  = ep + TOTAL;                       // TOTAL bytes
    uint16_t* d0 = (uint16_t*)(eg + TOTAL);          // TOTAL ushorts
    uint16_t* d1 = d0 + TOTAL;                       // TOTAL ushorts
    int* bigh    = (int*)(d1 + TOTAL);               // 4*HBINS ints
    int* smallh  = bigh + 4 * HBINS;                 // 4*NSMALL*LBINS ints
    int* psum    = smallh + 4 * NSMALL * LBINS;      // 4*NCH ints
    int* bar     = psum + 4 * NCH;                   // 1 int barrier counter

    hipMemsetAsync(bar, 0, sizeof(int), stream);
    hd95_mono<<<NB, NT, 0, stream>>>(pred, targ, ep, eg, d0, d1,
                                     bigh, smallh, psum, out, bar);
}

// Round 7
// 72.202 us; speedup vs baseline: 8.4683x; 8.4683x over previous
//
#include <hip/hip_runtime.h>
#include <stdint.h>

#define BB 2
#define DD 64
#define HH 128
#define WW 128
#define NVOX (DD*HH*WW)        // 2^20 per batch
#define TOTAL (BB*NVOX)        // 2097152
#define INF16 65535
#define HBINS 36868            // > max finite dsq (36227)
#define LBINS 4096
#define NSMALL 7
#define HISTINTS (4*HBINS + 4*NSMALL*LBINS)
#define TPITCH 132   // ushort pitch for xy tile
#define ZPITCH 68    // ushort pitch for z tile
#define CHUNK 40
#define NCH 922      // CHUNK*NCH = 36880 >= HBINS

// ---------- nearest set bit at position >= x in 128-bit mask (hi:lo) -------
__device__ __forceinline__ int dist128(uint64_t lo, uint64_t hi, int x)
{
    uint64_t a, b;
    if (x == 0)      { a = lo; b = hi; }
    else if (x < 64) { a = (lo >> x) | (hi << (64 - x)); b = hi >> x; }
    else             { a = hi >> (x - 64); b = 0; }
    if (a) return __builtin_ctzll(a);
    if (b) return 64 + __builtin_ctzll(b);
    return 999;
}

__device__ __forceinline__ uint32_t nib2bytes(uint32_t nib)
{
    return (nib & 1) | ((nib >> 1) & 1) << 8 | ((nib >> 2) & 1) << 16 | ((nib >> 3) & 1) << 24;
}

// ---------- fused: edges (6-neigh, border=False) + x-EDT + y-EDT ----------
// One block per (slice bz, dir). Also zeroes the histograms.
__global__ __launch_bounds__(1024)
void edges_edt_xy(const float* __restrict__ pred, const float* __restrict__ targ,
                  uint8_t* __restrict__ ep, uint8_t* __restrict__ eg,
                  uint16_t* __restrict__ d0, uint16_t* __restrict__ d1,
                  int* __restrict__ hist)
{
    __shared__ union {
        uint8_t  cmask[HH * WW];        // 16384 B
        uint16_t t16[HH * TPITCH];      // 33792 B
    } sm;
    int gid = blockIdx.x, tid = threadIdx.x;
    int gt = gid * 1024 + tid;
    if (gt < HISTINTS) hist[gt] = 0;

    int dir = gid & 1;
    int bz  = gid >> 1;                 // b*DD + z
    int z   = bz & (DD - 1);
    const float* src = dir ? pred : targ;   // dir0: EDT of targ(gt) edges
    uint8_t* emask   = dir ? ep : eg;
    uint16_t* dout   = dir ? d1 : d0;
    size_t sbase = (size_t)bz * (HH * WW);  // slice voxel base

    int row = tid >> 3;                 // y
    int seg = tid & 7;
    int x0 = seg * 16;

    // --- build center mask bits (16 voxels/thread) + z-neighbor bits ------
    const float4* s4 = (const float4*)src + (sbase >> 2) + tid * 4;
    uint32_t mbits = 0, zmbits = 0, zpbits = 0;
    #pragma unroll
    for (int j = 0; j < 4; ++j) {
        float4 c = s4[j];
        mbits |= ((uint32_t)(c.x > 0.5f) | (uint32_t)(c.y > 0.5f) << 1 |
                  (uint32_t)(c.z > 0.5f) << 2 | (uint32_t)(c.w > 0.5f) << 3) << (4 * j);
        if (z > 0) {
            float4 v = s4[j - (HH * WW) / 4];
            zmbits |= ((uint32_t)(v.x > 0.5f) | (uint32_t)(v.y > 0.5f) << 1 |
                       (uint32_t)(v.z > 0.5f) << 2 | (uint32_t)(v.w > 0.5f) << 3) << (4 * j);
        }
        if (z < DD - 1) {
            float4 v = s4[j + (HH * WW) / 4];
            zpbits |= ((uint32_t)(v.x > 0.5f) | (uint32_t)(v.y > 0.5f) << 1 |
                       (uint32_t)(v.z > 0.5f) << 2 | (uint32_t)(v.w > 0.5f) << 3) << (4 * j);
        }
        ((uint32_t*)sm.cmask)[tid * 4 + j] = nib2bytes((mbits >> (4 * j)) & 0xF);
    }
    __syncthreads();

    // --- erosion -> edge bits ---------------------------------------------
    uint32_t ebits = 0;
    #pragma unroll
    for (int i = 0; i < 16; ++i) {
        int x = x0 + i;
        bool m = (mbits >> i) & 1;
        bool e = false;
        if (m) {
            bool er = true;
            er = er && (x > 0)      && sm.cmask[row * WW + x - 1];
            er = er && (x < WW - 1) && sm.cmask[row * WW + x + 1];
            er = er && (row > 0)    && sm.cmask[(row - 1) * WW + x];
            er = er && (row < HH-1) && sm.cmask[(row + 1) * WW + x];
            er = er && (z > 0)      && ((zmbits >> i) & 1);
            er = er && (z < DD - 1) && ((zpbits >> i) & 1);
            e = !er;
        }
        ebits |= (uint32_t)e << i;
    }
    // write edge mask bytes (eval mask for the z-hist kernel)
    ((uint4*)(emask + sbase))[tid] = make_uint4(nib2bytes(ebits & 0xF),
                                                nib2bytes((ebits >> 4) & 0xF),
                                                nib2bytes((ebits >> 8) & 0xF),
                                                nib2bytes((ebits >> 12) & 0xF));
    __syncthreads();   // all cmask reads done; LDS reused for t16

    // --- x-EDT via 128-bit row bitmask (edge bits) -------------------------
    int lanebase = (tid & 63) & ~7;
    uint64_t lo = 0, hi = 0;
    #pragma unroll
    for (int j = 0; j < 4; ++j) {
        lo |= ((uint64_t)((uint32_t)__shfl((int)ebits, lanebase + j, 64) & 0xFFFFu)) << (16 * j);
        hi |= ((uint64_t)((uint32_t)__shfl((int)ebits, lanebase + 4 + j, 64) & 0xFFFFu)) << (16 * j);
    }
    uint64_t rlo = __brevll(hi), rhi = __brevll(lo);

    #pragma unroll
    for (int j = 0; j < 16; ++j) {
        int x = x0 + j;
        int dr = dist128(lo, hi, x);
        int dl = dist128(rlo, rhi, 127 - x);
        int dist = min(dr, dl);
        int dsq = (dist > 127) ? INF16 : dist * dist;
        sm.t16[row * TPITCH + x] = (uint16_t)dsq;
    }
    __syncthreads();

    // --- y-EDT (early-exit), write d ---------------------------------------
    int xx = tid & 127;
    int yg = tid >> 7;                  // 0..7
    for (int k = 0; k < 16; ++k) {
        int y = yg + k * 8;
        int best = sm.t16[y * TPITCH + xx];
        for (int o = 1; o < HH && o * o < best; ++o) {
            int osq = o * o;
            int ylo = y - o, yhi = y + o;
            if (ylo >= 0) best = min(best, (int)sm.t16[ylo * TPITCH + xx] + osq);
            if (yhi < HH) best = min(best, (int)sm.t16[yhi * TPITCH + xx] + osq);
        }
        dout[sbase + (size_t)y * WW + xx] = (uint16_t)best;
    }
}

// ---------- z EDT + histogram, both directions ----------------------------
__global__ __launch_bounds__(1024)
void edt_z_hist_kernel(const uint16_t* __restrict__ d0,
                       const uint16_t* __restrict__ d1,
                       const uint8_t* __restrict__ ep,
                       const uint8_t* __restrict__ eg,
                       int* __restrict__ bigh,
                       int* __restrict__ smallh)
{
    __shared__ uint16_t tile[DD * ZPITCH];
    __shared__ int lh[LBINS];
    int tid = threadIdx.x;           // 1024
    for (int t = tid; t < LBINS; t += 1024) lh[t] = 0;

    int blk = blockIdx.x;            // dir | xt<<1 | y<<2 | b<<9
    int dir = blk & 1;
    int xt  = (blk >> 1) & 1;
    int y   = (blk >> 2) & 127;
    int b   = blk >> 9;
    const uint16_t* d = dir ? d1 : d0;
    const uint8_t* evalmask = dir ? eg : ep;  // dir0: histogram at pred edges
    size_t base = (size_t)b * NVOX + (size_t)y * WW + xt * 64;

    {   // cooperative tile load: 64 z-rows x 128B
        int z = tid >> 4, sg = tid & 15;
        uint2 v = *(const uint2*)(d + base + (size_t)z * (HH * WW) + sg * 4);
        *(uint2*)&tile[z * ZPITCH + sg * 4] = v;
    }
    __syncthreads();

    int xx = tid & 63;
    int zg = tid >> 6;               // 0..15
    int g = b * 2 + dir;
    int* gbig = bigh + (size_t)g * HBINS;
    int lane = tid & 63;

    #pragma unroll
    for (int k = 0; k < 4; ++k) {
        int z = zg + k * 16;
        int best = tile[z * ZPITCH + xx];
        for (int o = 1; o < DD && o * o < best; ++o) {
            int osq = o * o;
            int zlo = z - o, zhi = z + o;
            if (zlo >= 0) best = min(best, (int)tile[zlo * ZPITCH + xx] + osq);
            if (zhi < DD) best = min(best, (int)tile[zhi * ZPITCH + xx] + osq);
        }
        int v = best; if (v >= HBINS) v = HBINS - 1;
        bool valid = evalmask[base + (size_t)z * (HH * WW) + xx] != 0;
        unsigned long long active = __ballot(valid);
        while (active) {
            int leader = __ffsll(active) - 1;
            int lv = __shfl(v, leader, 64);
            unsigned long long same = __ballot(valid && (v == lv));
            if (lane == leader) {
                int cnt = __popcll(same);
                if (lv < LBINS) atomicAdd(&lh[lv], cnt);
                else            atomicAdd(&gbig[lv], cnt);
            }
            active &= ~same;
        }
    }
    __syncthreads();
    int slot = (blk >> 1) & 7;       // spread flush over 8 targets per g
    int* dst = (slot == 0) ? gbig : (smallh + ((size_t)g * NSMALL + (slot - 1)) * LBINS);
    for (int t = tid; t < LBINS; t += 1024) {
        int c = lh[t];
        if (c) atomicAdd(&dst[t], c);
    }
}

// ---------- fold + percentile + final max (one block per g) ----------------
__global__ __launch_bounds__(1024)
void fold_percentile_kernel(int* __restrict__ bigh,
                            const int* __restrict__ smallh,
                            float* __restrict__ out)
{
    __shared__ int ps[1024];
    __shared__ int chunkidx, chunkbase;
    __shared__ int sel[2];
    int g = blockIdx.x;
    int tid = threadIdx.x;           // 1024
    int* gbig = bigh + (size_t)g * HBINS;

    // fold shadow histograms into bigh (low LBINS bins)
    for (int t = tid; t < LBINS; t += 1024) {
        const int* gs = smallh + (size_t)g * NSMALL * LBINS + t;
        int v = gbig[t];
        #pragma unroll
        for (int s = 0; s < NSMALL; ++s) v += gs[s * LBINS];
        gbig[t] = v;
    }
    if (tid == 0) { chunkidx = 0; chunkbase = 0; sel[0] = 0; sel[1] = 0; }
    __syncthreads();

    // per-chunk sums: thread t sums bins [t*40, t*40+40) via 10 uint4 loads
    int part = 0;
    if (tid < NCH) {
        const uint4* p = (const uint4*)(gbig + tid * CHUNK);
        #pragma unroll
        for (int j = 0; j < CHUNK / 4; ++j) {
            int bin0 = tid * CHUNK + j * 4;
            uint4 v = p[j];
            if (bin0 + 3 < HBINS) part += (int)(v.x + v.y + v.z + v.w);
            else {
                if (bin0 + 0 < HBINS) part += (int)v.x;
                if (bin0 + 1 < HBINS) part += (int)v.y;
                if (bin0 + 2 < HBINS) part += (int)v.z;
                if (bin0 + 3 < HBINS) part += (int)v.w;
            }
        }
    }
    ps[tid] = part;
    __syncthreads();
    for (int o = 1; o < 1024; o <<= 1) {
        int t = (tid >= o) ? ps[tid - o] : 0;
        __syncthreads();
        ps[tid] += t;
        __syncthreads();
    }
    int n = ps[1023];
    int incl = ps[tid];
    int excl = incl - part;

    float pos = 0.95f * (float)(n - 1);
    float fpos = floorf(pos);
    int lo = (int)fpos;
    int nm1 = n - 1; if (nm1 < 0) nm1 = 0;
    if (lo < 0) lo = 0;
    if (lo > nm1) lo = nm1;
    int hi = lo + 1; if (hi > nm1) hi = nm1;
    float frac = pos - fpos;

    for (int ri = 0; ri < 2; ++ri) {
        int r = ri ? hi : lo;
        if (r >= excl && r < incl) { chunkidx = tid; chunkbase = excl; }  // unique owner
        __syncthreads();
        if (tid == 0) {
            int c = chunkidx, cum = chunkbase;
            int binsel = 0;
            for (int j = 0; j < CHUNK; ++j) {
                int t2 = c * CHUNK + j;
                if (t2 >= HBINS) break;
                cum += gbig[t2];
                if (cum > r) { binsel = t2; break; }
            }
            sel[ri] = binsel;
        }
        __syncthreads();
    }
    if (tid == 0) {
        float a = sqrtf((float)sel[0]);
        float bv = sqrtf((float)sel[1]);
        float val = a + frac * (bv - a);
        atomicMax((int*)out + (g >> 1), __float_as_int(val));  // val>=0: int order ok
    }
}

extern "C" void kernel_launch(void* const* d_in, const int* in_sizes, int n_in,
                              void* d_out, int out_size, void* d_ws, size_t ws_size,
                              hipStream_t stream)
{
    const float* pred = (const float*)d_in[0];
    const float* targ = (const float*)d_in[1];
    float* out = (float*)d_out;

    uint8_t* ws = (uint8_t*)d_ws;
    uint8_t* ep  = ws;                               // TOTAL bytes
    uint8_t* eg  = ep + TOTAL;                       // TOTAL bytes
    uint16_t* d0 = (uint16_t*)(eg + TOTAL);          // TOTAL ushorts
    uint16_t* d1 = d0 + TOTAL;                       // TOTAL ushorts
    int* bigh    = (int*)(d1 + TOTAL);               // 4*HBINS ints
    int* smallh  = bigh + 4 * HBINS;                 // 4*NSMALL*LBINS ints

    edges_edt_xy<<<BB*DD*2, 1024, 0, stream>>>(pred, targ, ep, eg, d0, d1, bigh);
    edt_z_hist_kernel<<<BB*HH*2*2, 1024, 0, stream>>>(d0, d1, ep, eg, bigh, smallh);
    fold_percentile_kernel<<<4, 1024, 0, stream>>>(bigh, smallh, out);
}

// Round 8
// 48.418 us; speedup vs baseline: 12.6282x; 1.4912x over previous
//
#include <hip/hip_runtime.h>
#include <stdint.h>

#define BB 2
#define DD 64
#define HH 128
#define WW 128
#define NVOX (DD*HH*WW)        // 2^20 per batch
#define TOTAL (BB*NVOX)        // 2097152
#define INF16 65535
#define HBINS 36868            // > max finite dsq (36227)
#define LBINS 4096
#define NSMALL 7
#define HISTINTS (4*HBINS + 4*NSMALL*LBINS)    // 262160, bigh||smallh contiguous
#define NWORDS (TOTAL/16)      // 131072 uint16 mask words per volume
#define TPITCH 130   // ushort pitch for xy tile (odd dword stride -> conflict-free)
#define ZPITCH 68    // ushort pitch for z tile
#define CHUNK 40
#define NCH 922      // CHUNK*NCH = 36880 >= HBINS

// ---------- nearest set bit at position >= x in 128-bit mask (hi:lo) -------
__device__ __forceinline__ int dist128(uint64_t lo, uint64_t hi, int x)
{
    uint64_t a, b;
    if (x == 0)      { a = lo; b = hi; }
    else if (x < 64) { a = (lo >> x) | (hi << (64 - x)); b = hi >> x; }
    else             { a = hi >> (x - 64); b = 0; }
    if (a) return __builtin_ctzll(a);
    if (b) return 64 + __builtin_ctzll(b);
    return 999;
}

// ---------- bitpack: float>0.5 masks -> 16-voxel uint16 words; zero hist ---
__global__ __launch_bounds__(256)
void bitpack_kernel(const float* __restrict__ pred, const float* __restrict__ targ,
                    uint16_t* __restrict__ pb, uint16_t* __restrict__ tb,
                    int* __restrict__ hist)
{
    int gt = blockIdx.x * 256 + threadIdx.x;       // 0..NWORDS-1
    for (int t = gt; t < HISTINTS; t += NWORDS) hist[t] = 0;

    const float4* p4 = (const float4*)pred + gt * 4;
    const float4* t4 = (const float4*)targ + gt * 4;
    uint32_t pbits = 0, tbits = 0;
    #pragma unroll
    for (int j = 0; j < 4; ++j) {
        float4 v = p4[j];
        pbits |= ((uint32_t)(v.x > 0.5f) | (uint32_t)(v.y > 0.5f) << 1 |
                  (uint32_t)(v.z > 0.5f) << 2 | (uint32_t)(v.w > 0.5f) << 3) << (4 * j);
        float4 w = t4[j];
        tbits |= ((uint32_t)(w.x > 0.5f) | (uint32_t)(w.y > 0.5f) << 1 |
                  (uint32_t)(w.z > 0.5f) << 2 | (uint32_t)(w.w > 0.5f) << 3) << (4 * j);
    }
    pb[gt] = (uint16_t)pbits;
    tb[gt] = (uint16_t)tbits;
}

// ---------- edges (bit-ops) + x-EDT (bitmask) + y-EDT (LDS) ----------------
// One block per (slice bz, dir). dir0: EDT of targ(gt) edges -> d0, writes egb.
__global__ __launch_bounds__(1024)
void edt_xy_kernel(const uint16_t* __restrict__ pb, const uint16_t* __restrict__ tb,
                   uint16_t* __restrict__ epb, uint16_t* __restrict__ egb,
                   uint16_t* __restrict__ d0, uint16_t* __restrict__ d1)
{
    __shared__ uint16_t w16[1024];
    __shared__ uint16_t t16[HH * TPITCH];
    int gid = blockIdx.x, tid = threadIdx.x;
    int dir = gid & 1;
    int bz  = gid >> 1;                 // b*DD + z
    int z   = bz & (DD - 1);
    const uint16_t* src = dir ? pb : tb;
    uint16_t* eout      = dir ? epb : egb;
    uint16_t* dout      = dir ? d1 : d0;
    int wbase = bz * 1024;              // word index of slice start
    size_t sbase = (size_t)bz * (HH * WW);

    int row = tid >> 3;                 // y
    int seg = tid & 7;
    int x0 = seg * 16;

    uint32_t m  = src[wbase + tid];
    uint32_t zm = (z > 0)      ? src[wbase + tid - 1024] : 0;
    uint32_t zp = (z < DD - 1) ? src[wbase + tid + 1024] : 0;
    w16[tid] = (uint16_t)m;
    __syncthreads();
    uint32_t ym = (row > 0)      ? w16[tid - 8] : 0;
    uint32_t yp = (row < HH - 1) ? w16[tid + 8] : 0;
    uint32_t lw = (seg > 0)      ? w16[tid - 1] : 0;
    uint32_t nw = (seg < 7)      ? w16[tid + 1] : 0;
    uint32_t L = ((m << 1) | (lw >> 15)) & 0xFFFFu;
    uint32_t R = ((m >> 1) | ((nw & 1u) << 15)) & 0xFFFFu;
    uint32_t er = m & L & R & ym & yp & zm & zp;
    uint32_t eb = m & ~er;              // edge bits (16)
    eout[wbase + tid] = (uint16_t)eb;

    // --- x-EDT via 128-bit row bitmask of edge bits ------------------------
    int lanebase = (tid & 63) & ~7;
    uint64_t lo = 0, hi = 0;
    #pragma unroll
    for (int j = 0; j < 4; ++j) {
        lo |= ((uint64_t)((uint32_t)__shfl((int)eb, lanebase + j, 64) & 0xFFFFu)) << (16 * j);
        hi |= ((uint64_t)((uint32_t)__shfl((int)eb, lanebase + 4 + j, 64) & 0xFFFFu)) << (16 * j);
    }
    uint64_t rlo = __brevll(hi), rhi = __brevll(lo);

    #pragma unroll
    for (int j = 0; j < 16; ++j) {
        int x = x0 + j;
        int dr = dist128(lo, hi, x);
        int dl = dist128(rlo, rhi, 127 - x);
        int dist = min(dr, dl);
        int dsq = (dist > 127) ? INF16 : dist * dist;
        t16[row * TPITCH + x] = (uint16_t)dsq;
    }
    __syncthreads();

    // --- y-EDT (early-exit), write d ---------------------------------------
    int xx = tid & 127;
    int yg = tid >> 7;                  // 0..7
    for (int k = 0; k < 16; ++k) {
        int y = yg + k * 8;
        int best = t16[y * TPITCH + xx];
        for (int o = 1; o < HH && o * o < best; ++o) {
            int osq = o * o;
            int ylo = y - o, yhi = y + o;
            if (ylo >= 0) best = min(best, (int)t16[ylo * TPITCH + xx] + osq);
            if (yhi < HH) best = min(best, (int)t16[yhi * TPITCH + xx] + osq);
        }
        dout[sbase + (size_t)y * WW + xx] = (uint16_t)best;
    }
}

// ---------- z EDT + histogram, both directions ----------------------------
__global__ __launch_bounds__(1024)
void edt_z_hist_kernel(const uint16_t* __restrict__ d0,
                       const uint16_t* __restrict__ d1,
                       const uint16_t* __restrict__ epb,
                       const uint16_t* __restrict__ egb,
                       int* __restrict__ bigh,
                       int* __restrict__ smallh)
{
    __shared__ uint16_t tile[DD * ZPITCH];
    __shared__ int lh[LBINS];
    int tid = threadIdx.x;           // 1024
    for (int t = tid; t < LBINS; t += 1024) lh[t] = 0;

    int blk = blockIdx.x;            // dir | xt<<1 | y<<2 | b<<9
    int dir = blk & 1;
    int xt  = (blk >> 1) & 1;
    int y   = (blk >> 2) & 127;
    int b   = blk >> 9;
    const uint16_t* d = dir ? d1 : d0;
    const uint16_t* evalbits = dir ? egb : epb;  // dir0: histogram at pred edges
    size_t base = (size_t)b * NVOX + (size_t)y * WW + xt * 64;

    {   // cooperative tile load: 64 z-rows x 128B
        int z = tid >> 4, sg = tid & 15;
        uint2 v = *(const uint2*)(d + base + (size_t)z * (HH * WW) + sg * 4);
        *(uint2*)&tile[z * ZPITCH + sg * 4] = v;
    }
    __syncthreads();

    int xx = tid & 63;
    int zg = tid >> 6;               // 0..15
    int x  = xt * 64 + xx;
    int g = b * 2 + dir;
    int* gbig = bigh + (size_t)g * HBINS;
    int lane = tid & 63;

    #pragma unroll
    for (int k = 0; k < 4; ++k) {
        int z = zg + k * 16;
        int best = tile[z * ZPITCH + xx];
        for (int o = 1; o < DD && o * o < best; ++o) {
            int osq = o * o;
            int zlo = z - o, zhi = z + o;
            if (zlo >= 0) best = min(best, (int)tile[zlo * ZPITCH + xx] + osq);
            if (zhi < DD) best = min(best, (int)tile[zhi * ZPITCH + xx] + osq);
        }
        int v = best; if (v >= HBINS) v = HBINS - 1;
        uint32_t ew = evalbits[((b * DD + z) * HH + y) * 8 + (x >> 4)];
        bool valid = (ew >> (x & 15)) & 1;
        unsigned long long active = __ballot(valid);
        while (active) {
            int leader = __ffsll(active) - 1;
            int lv = __shfl(v, leader, 64);
            unsigned long long same = __ballot(valid && (v == lv));
            if (lane == leader) {
                int cnt = __popcll(same);
                if (lv < LBINS) atomicAdd(&lh[lv], cnt);
                else            atomicAdd(&gbig[lv], cnt);
            }
            active &= ~same;
        }
    }
    __syncthreads();
    int slot = (blk >> 1) & 7;       // spread flush over 8 targets per g
    int* dst = (slot == 0) ? gbig : (smallh + ((size_t)g * NSMALL + (slot - 1)) * LBINS);
    for (int t = tid; t < LBINS; t += 1024) {
        int c = lh[t];
        if (c) atomicAdd(&dst[t], c);
    }
}

// ---------- fold + percentile + final max (one block per g) ----------------
__global__ __launch_bounds__(1024)
void fold_percentile_kernel(int* __restrict__ bigh,
                            const int* __restrict__ smallh,
                            float* __restrict__ out)
{
    __shared__ int ps[1024];
    __shared__ int chunkidx, chunkbase;
    __shared__ int sel[2];
    int g = blockIdx.x;
    int tid = threadIdx.x;           // 1024
    int* gbig = bigh + (size_t)g * HBINS;

    // fold shadow histograms into bigh (low LBINS bins)
    for (int t = tid; t < LBINS; t += 1024) {
        const int* gs = smallh + (size_t)g * NSMALL * LBINS + t;
        int v = gbig[t];
        #pragma unroll
        for (int s = 0; s < NSMALL; ++s) v += gs[s * LBINS];
        gbig[t] = v;
    }
    if (tid == 0) { chunkidx = 0; chunkbase = 0; sel[0] = 0; sel[1] = 0; }
    __syncthreads();

    // per-chunk sums: thread t sums bins [t*40, t*40+40)
    int part = 0;
    if (tid < NCH) {
        const uint4* p = (const uint4*)(gbig + tid * CHUNK);
        #pragma unroll
        for (int j = 0; j < CHUNK / 4; ++j) {
            int bin0 = tid * CHUNK + j * 4;
            uint4 v = p[j];
            if (bin0 + 3 < HBINS) part += (int)(v.x + v.y + v.z + v.w);
            else {
                if (bin0 + 0 < HBINS) part += (int)v.x;
                if (bin0 + 1 < HBINS) part += (int)v.y;
                if (bin0 + 2 < HBINS) part += (int)v.z;
                if (bin0 + 3 < HBINS) part += (int)v.w;
            }
        }
    }
    ps[tid] = part;
    __syncthreads();
    for (int o = 1; o < 1024; o <<= 1) {
        int t = (tid >= o) ? ps[tid - o] : 0;
        __syncthreads();
        ps[tid] += t;
        __syncthreads();
    }
    int n = ps[1023];
    int incl = ps[tid];
    int excl = incl - part;

    float pos = 0.95f * (float)(n - 1);
    float fpos = floorf(pos);
    int lo = (int)fpos;
    int nm1 = n - 1; if (nm1 < 0) nm1 = 0;
    if (lo < 0) lo = 0;
    if (lo > nm1) lo = nm1;
    int hi = lo + 1; if (hi > nm1) hi = nm1;
    float frac = pos - fpos;

    for (int ri = 0; ri < 2; ++ri) {
        int r = ri ? hi : lo;
        if (r >= excl && r < incl) { chunkidx = tid; chunkbase = excl; }  // unique owner
        __syncthreads();
        if (tid == 0) {
            int c = chunkidx, cum = chunkbase;
            int binsel = 0;
            for (int j = 0; j < CHUNK; ++j) {
                int t2 = c * CHUNK + j;
                if (t2 >= HBINS) break;
                cum += gbig[t2];
                if (cum > r) { binsel = t2; break; }
            }
            sel[ri] = binsel;
        }
        __syncthreads();
    }
    if (tid == 0) {
        float a = sqrtf((float)sel[0]);
        float bv = sqrtf((float)sel[1]);
        float val = a + frac * (bv - a);
        atomicMax((int*)out + (g >> 1), __float_as_int(val));  // val>=0: int order ok
    }
}

extern "C" void kernel_launch(void* const* d_in, const int* in_sizes, int n_in,
                              void* d_out, int out_size, void* d_ws, size_t ws_size,
                              hipStream_t stream)
{
    const float* pred = (const float*)d_in[0];
    const float* targ = (const float*)d_in[1];
    float* out = (float*)d_out;

    uint8_t* ws = (uint8_t*)d_ws;
    uint16_t* pb  = (uint16_t*)ws;                   // NWORDS u16 (pred mask bits)
    uint16_t* tb  = pb + NWORDS;                     // NWORDS u16 (targ mask bits)
    uint16_t* epb = tb + NWORDS;                     // NWORDS u16 (pred edge bits)
    uint16_t* egb = epb + NWORDS;                    // NWORDS u16 (targ edge bits)
    uint16_t* d0  = egb + NWORDS;                    // TOTAL u16
    uint16_t* d1  = d0 + TOTAL;                      // TOTAL u16
    int* bigh     = (int*)(d1 + TOTAL);              // 4*HBINS ints
    int* smallh   = bigh + 4 * HBINS;                // 4*NSMALL*LBINS ints (contiguous)

    bitpack_kernel<<<NWORDS/256, 256, 0, stream>>>(pred, targ, pb, tb, bigh);
    edt_xy_kernel<<<BB*DD*2, 1024, 0, stream>>>(pb, tb, epb, egb, d0, d1);
    edt_z_hist_kernel<<<BB*HH*2*2, 1024, 0, stream>>>(d0, d1, epb, egb, bigh, smallh);
    fold_percentile_kernel<<<4, 1024, 0, stream>>>(bigh, smallh, out);
}